// Round 1
// baseline (1095.695 us; speedup 1.0000x reference)
//
#include <hip/hip_runtime.h>
#include <math.h>

#define F_ 48
#define G_ 4
#define C_ 128
#define HW 16384
#define SCALE_C 0.999f
#define TPB 256
#define TILE 64

// ws float offsets
#define WS_WT    0            // [128][192]  WT[c][f*4+g] = Wf[g][f][c]
#define WS_W2    24576        // [192][128]  W2[f*4+g][c] = Wf[g][f][c]
#define WS_QE    49152        // [48][4][4]  (l,g)  Q/sigma^2
#define WS_QN    49920        // [48][4][4]  (g,l)  Q
#define WS_QS    50688        // [48]        SCALE/taus
#define WS_SCAL  50736        // [2][48]
#define WS_ISCAL 50832        // [2][48]
#define WS_MISC  50928        // lamb_e, eps_e, inv_denom

__global__ void setup_kernel(const float* __restrict__ sigma,
                             const float* __restrict__ Qp,
                             const float* __restrict__ taus_p,
                             const float* __restrict__ lamb,
                             const float* __restrict__ eps_om,
                             const float* __restrict__ mw1, const float* __restrict__ mb1,
                             const float* __restrict__ mw2, const float* __restrict__ mb2,
                             const float* __restrict__ mw3, const float* __restrict__ mb3,
                             const float* __restrict__ Wf,
                             float* __restrict__ ws)
{
    const int tid = threadIdx.x;
    // Transposed/reordered copies of Wf (row = f*4+g, f-major)
    for (int i = tid; i < G_ * F_ * C_; i += TPB) {
        int g = i / (F_ * C_);
        int f = (i / C_) % F_;
        int c = i % C_;
        float v = Wf[i];
        int row = f * 4 + g;
        ws[WS_WT + c * 192 + row] = v;
        ws[WS_W2 + row * 128 + c] = v;
    }
    if (tid < F_) {
        const int f = tid;
        // L1 row normalization (axis=2 of Q_param[f,g,l])
        float Qm[4][4];
        for (int g = 0; g < 4; ++g) {
            float s = 0.f;
            for (int l = 0; l < 4; ++l) s += fabsf(Qp[f * 16 + g * 4 + l]);
            float d = fmaxf(s, 1.0f);
            for (int l = 0; l < 4; ++l) Qm[g][l] = Qp[f * 16 + g * 4 + l] / d;
        }
        // A = Q^T Q (4x4 SPD); lambda_max(A) = sigma_max(Q)^2
        double A[4][4];
        for (int i = 0; i < 4; ++i)
            for (int j = 0; j < 4; ++j) {
                double s = 0.0;
                for (int g = 0; g < 4; ++g) s += (double)Qm[g][i] * (double)Qm[g][j];
                A[i][j] = s;
            }
        // repeated squaring (normalized) -> rank-collapses onto top eigenspace
        double M[4][4];
        for (int i = 0; i < 4; ++i) for (int j = 0; j < 4; ++j) M[i][j] = A[i][j];
        for (int it = 0; it < 30; ++it) {
            double T[4][4]; double mx = 0.0;
            for (int i = 0; i < 4; ++i)
                for (int j = 0; j < 4; ++j) {
                    double s = 0.0;
                    for (int k = 0; k < 4; ++k) s += M[i][k] * M[k][j];
                    T[i][j] = s;
                    double a = fabs(s); if (a > mx) mx = a;
                }
            if (mx < 1e-300) break;
            double inv = 1.0 / mx;
            for (int i = 0; i < 4; ++i) for (int j = 0; j < 4; ++j) M[i][j] = T[i][j] * inv;
        }
        // top eigenvector ~ dominant column; Rayleigh quotient with original A
        int jb = 0; double bn = -1.0;
        for (int j = 0; j < 4; ++j) {
            double n = 0.0;
            for (int i = 0; i < 4; ++i) n += M[i][j] * M[i][j];
            if (n > bn) { bn = n; jb = j; }
        }
        double v[4]; for (int i = 0; i < 4; ++i) v[i] = M[i][jb];
        double Av[4];
        for (int i = 0; i < 4; ++i) {
            double s = 0.0;
            for (int j = 0; j < 4; ++j) s += A[i][j] * v[j];
            Av[i] = s;
        }
        double vv = 0.0, vav = 0.0;
        for (int i = 0; i < 4; ++i) { vv += v[i] * v[i]; vav += v[i] * Av[i]; }
        double lam = (vv > 0.0) ? (vav / vv) : 0.0;
        float lamf = (float)lam;
        for (int l = 0; l < 4; ++l)
            for (int g = 0; g < 4; ++g)
                ws[WS_QE + f * 16 + l * 4 + g] = Qm[l][g] / lamf;
        for (int g = 0; g < 4; ++g)
            for (int l = 0; l < 4; ++l)
                ws[WS_QN + f * 16 + g * 4 + l] = Qm[g][l];
        float tau = expf(fmaxf(taus_p[f], 0.0f));
        ws[WS_QS + f] = SCALE_C / tau;
    }
    if (tid == 0) {
        float lamb_e = expf(lamb[0]);
        float eps_e  = expf(eps_om[0]);
        ws[WS_MISC + 0] = lamb_e;
        ws[WS_MISC + 1] = eps_e;
        ws[WS_MISC + 2] = 1.0f / (1.0f + lamb_e * (1.0f + eps_e));
        for (int b = 0; b < 2; ++b) {
            float sg = sigma[b];
            float t = sg * 20.0f - 2.0f;
            float h1[F_], h2[F_];
            for (int j = 0; j < F_; ++j) h1[j] = fmaxf(t * mw1[j] + mb1[j], 0.0f);
            for (int j = 0; j < F_; ++j) {
                float s = mb2[j];
                for (int k = 0; k < F_; ++k) s += h1[k] * mw2[k * F_ + j];
                h2[j] = fmaxf(s, 0.0f);
            }
            for (int j = 0; j < F_; ++j) {
                float s = mb3[j];
                for (int k = 0; k < F_; ++k) s += h2[k] * mw3[k * F_ + j];
                float sc = fmaxf(s * 0.05f + sg, 0.0f) * 1.0f + 1e-9f;
                ws[WS_SCAL + b * F_ + j] = sc;
                ws[WS_ISCAL + b * F_ + j] = 1.0f / sc;
            }
        }
    }
}

// Euclidean projection of a 4-vector onto the unit l1 ball (per lane, in regs)
__device__ __forceinline__ void proj4(const float v[4], float o[4]) {
    float a0 = fabsf(v[0]), a1 = fabsf(v[1]), a2 = fabsf(v[2]), a3 = fabsf(v[3]);
    float sum = a0 + a1 + a2 + a3;
    // 5-comparator sorting network, descending
    float t0 = fmaxf(a0, a1), u0 = fminf(a0, a1);
    float t1 = fmaxf(a2, a3), u1 = fminf(a2, a3);
    float s0 = fmaxf(t0, t1), m0 = fminf(t0, t1);
    float m1 = fmaxf(u0, u1), s3 = fminf(u0, u1);
    float s1 = fmaxf(m1, m0), s2 = fminf(m1, m0);
    float c2 = s0 + s1, c3 = c2 + s2, c4 = c3 + s3;
    float th = s0 - 1.0f, rh = 1.0f;   // cond_1 always true
    if (s1 * 2.0f > c2 - 1.0f) { th = c2 - 1.0f; rh = 2.0f; }
    if (s2 * 3.0f > c3 - 1.0f) { th = c3 - 1.0f; rh = 3.0f; }
    if (s3 * 4.0f > c4 - 1.0f) { th = c4 - 1.0f; rh = 4.0f; }
    float theta = fmaxf(th / rh, 0.0f);
    bool inside = (sum <= 1.0f);
#pragma unroll
    for (int g = 0; g < 4; ++g) {
        float ag = fabsf(v[g]);
        float pg = copysignf(fmaxf(ag - theta, 0.0f), v[g]);
        o[g] = inside ? v[g] : pg;
    }
}

__global__ __launch_bounds__(TPB, 2) void mfoe_main(
    const float* __restrict__ xnoisy,
    const float* __restrict__ ws,
    float* __restrict__ out,
    const int* __restrict__ n_iter_p)
{
    __shared__ float xt[C_][TILE];     // 32 KB, current x tile [c][p]
    __shared__ float actS[96][TILE];   // 24 KB, half of the (f,g) rows

    const int tid  = threadIdx.x;
    const int lane = tid & 63;
    const int wu   = __builtin_amdgcn_readfirstlane((int)(tid >> 6));
    const int blk  = blockIdx.x;
    const int b    = blk >> 8;            // 256 tiles per image
    const int pix0 = (blk & 255) << 6;

    const float* __restrict__ xin  = xnoisy + b * (C_ * HW) + pix0;
    float* __restrict__       oimg = out    + b * (C_ * HW) + pix0;

    // stage x_noisy tile into LDS (coalesced)
    for (int i = tid; i < C_ * TILE; i += TPB) {
        int c = i >> 6, p = i & 63;
        xt[c][p] = xin[c * HW + p];
    }
    __syncthreads();

    const int c0 = wu * 32;
    float xnr[32];                         // this thread's x_noisy slice, kept in regs
#pragma unroll
    for (int i = 0; i < 32; ++i) xnr[i] = xt[c0 + i][lane];

    const float lamb_e = ws[WS_MISC + 0];
    const float eps_e  = ws[WS_MISC + 1];
    const float invden = ws[WS_MISC + 2];
    const int   niter  = *n_iter_p;

    const float* __restrict__ WT = ws + WS_WT;
    const float* __restrict__ W2 = ws + WS_W2;

    for (int it = 0; it < niter; ++it) {
        float go[32];
#pragma unroll
        for (int i = 0; i < 32; ++i) go[i] = 0.0f;

        for (int half = 0; half < 2; ++half) {
            // ---- pass 1: Lx rows for f in [half*24 + wu*6, +6), 2 f per block of 8 rows
            for (int fb = 0; fb < 3; ++fb) {
                const int f0 = half * 24 + wu * 6 + fb * 2;
                const int r0 = f0 * 4;
                float acc[8];
#pragma unroll
                for (int j = 0; j < 8; ++j) acc[j] = 0.0f;
#pragma unroll 4
                for (int c = 0; c < C_; ++c) {
                    float xv = xt[c][lane];
                    const float* wp = WT + c * 192 + r0;   // wave-uniform -> s_load
#pragma unroll
                    for (int j = 0; j < 8; ++j) acc[j] = fmaf(wp[j], xv, acc[j]);
                }
#pragma unroll
                for (int fi = 0; fi < 2; ++fi) {
                    const int f = f0 + fi;
                    const float invs = ws[WS_ISCAL + b * F_ + f];
                    const float scl  = ws[WS_SCAL  + b * F_ + f];
                    const float qsv  = ws[WS_QS + f];
                    const float* qe = ws + WS_QE + f * 16;
                    const float* qn = ws + WS_QN + f * 16;
                    float v[4];
#pragma unroll
                    for (int g = 0; g < 4; ++g) v[g] = acc[fi * 4 + g] * invs;
                    // activation (all in registers, no cross-lane)
                    float pv[4]; proj4(v, pv);
                    float y[4];
#pragma unroll
                    for (int l = 0; l < 4; ++l)
                        y[l] = qsv * (qe[l*4+0]*v[0] + qe[l*4+1]*v[1] + qe[l*4+2]*v[2] + qe[l*4+3]*v[3]);
                    float py[4]; proj4(y, py);
                    float m2[4];
#pragma unroll
                    for (int g = 0; g < 4; ++g) m2[g] = fmaf(eps_e, y[g], py[g]);
                    const int lrow = (f - half * 24) * 4;
#pragma unroll
                    for (int l = 0; l < 4; ++l) {
                        float gcc = SCALE_C * (qn[0*4+l]*m2[0] + qn[1*4+l]*m2[1] +
                                               qn[2*4+l]*m2[2] + qn[3*4+l]*m2[3]);
                        float gc = fmaf(eps_e, v[l], pv[l]);
                        actS[lrow + l][lane] = lamb_e * (gc - gcc) * scl;
                    }
                }
            }
            __syncthreads();
            // ---- pass 2 (partial): go[c] += W2[row][c] * actS[row][p]
#pragma unroll 2
            for (int lr = 0; lr < 96; ++lr) {
                const int R = half * 96 + lr;
                float a = actS[lr][lane];
                const float* wp = W2 + R * 128 + c0;       // wave-uniform -> s_load
#pragma unroll
                for (int i = 0; i < 32; ++i) go[i] = fmaf(wp[i], a, go[i]);
            }
            __syncthreads();
        }
        // ---- update (each thread owns its (c-range, p) cells; in-place safe)
        const bool last = (it == niter - 1);
#pragma unroll
        for (int i = 0; i < 32; ++i) {
            float xv = xt[c0 + i][lane];
            float nx = xv - (xv - xnr[i] + go[i]) * invden;
            xt[c0 + i][lane] = nx;
            if (last) oimg[(c0 + i) * HW + lane] = nx;
        }
        __syncthreads();
    }
    if (niter == 0) {
        for (int i = tid; i < C_ * TILE; i += TPB) {
            int c = i >> 6, p = i & 63;
            oimg[c * HW + p] = xt[c][p];
        }
    }
}

extern "C" void kernel_launch(void* const* d_in, const int* in_sizes, int n_in,
                              void* d_out, int out_size, void* d_ws, size_t ws_size,
                              hipStream_t stream) {
    const float* x_noisy = (const float*)d_in[0];
    const float* sigma   = (const float*)d_in[1];
    const float* Qp      = (const float*)d_in[2];
    const float* taus_p  = (const float*)d_in[3];
    const float* lamb    = (const float*)d_in[4];
    const float* eps_om  = (const float*)d_in[5];
    const float* mw1     = (const float*)d_in[6];
    const float* mb1     = (const float*)d_in[7];
    const float* mw2     = (const float*)d_in[8];
    const float* mb2     = (const float*)d_in[9];
    const float* mw3     = (const float*)d_in[10];
    const float* mb3     = (const float*)d_in[11];
    const float* Wf      = (const float*)d_in[12];
    const int*   n_iter  = (const int*)d_in[13];
    float* out = (float*)d_out;
    float* ws  = (float*)d_ws;

    hipLaunchKernelGGL(setup_kernel, dim3(1), dim3(TPB), 0, stream,
                       sigma, Qp, taus_p, lamb, eps_om,
                       mw1, mb1, mw2, mb2, mw3, mb3, Wf, ws);
    hipLaunchKernelGGL(mfoe_main, dim3(512), dim3(TPB), 0, stream,
                       x_noisy, ws, out, n_iter);
}